// Round 15
// baseline (242.054 us; speedup 1.0000x reference)
//
#include <hip/hip_runtime.h>
#include <hip/hip_bf16.h>
#include <math.h>

typedef __attribute__((ext_vector_type(8))) short short8;
typedef __attribute__((ext_vector_type(4))) float f32x4;
typedef __attribute__((ext_vector_type(4))) unsigned short us4;

#define MFMA_BF16 __builtin_amdgcn_mfma_f32_16x16x32_bf16

__device__ __forceinline__ float b2f(unsigned short u) {
    union { unsigned int i; float f; } v; v.i = ((unsigned int)u) << 16; return v.f;
}
__device__ __forceinline__ unsigned short f2b(float f) {
    __hip_bfloat16 h = __float2bfloat16(f);
    return *reinterpret_cast<unsigned short*>(&h);
}

// ---------------------------------------------------------------------------
// K0: h_grid (128,128ch,64x64) fp32 -> ht (128,4096px,128ch) bf16  (~50us)
// ---------------------------------------------------------------------------
__global__ __launch_bounds__(256) void transpose_h(const float* __restrict__ hg,
                                                   unsigned short* __restrict__ ht) {
    __shared__ float t[128][65];
    int bid = blockIdx.x;                        // 8192 = 8 xcd * 1024
    int x = bid & 7, r = bid >> 3;
    int n = x * 16 + (r & 15);                   // image pinned to xcd
    int pb = r >> 4;
    int tid = threadIdx.x;
    const float* src = hg + (size_t)n * 128 * 4096 + pb * 64;
    int j = tid & 63, i0 = tid >> 6;
#pragma unroll
    for (int ii = 0; ii < 32; ++ii) {
        int ch = ii * 4 + i0;
        t[ch][j] = src[(size_t)ch * 4096 + j];
    }
    __syncthreads();
#pragma unroll
    for (int it = 0; it < 8; ++it) {
        int idx = tid + it * 256;
        int px = idx >> 5, cq = idx & 31;
        us4 o;
#pragma unroll
        for (int rr = 0; rr < 4; ++rr) o[rr] = f2b(t[cq * 4 + rr][px]);
        *(us4*)&ht[((size_t)n * 4096 + pb * 64 + px) * 128 + cq * 4] = o;
    }
}

// ---------------------------------------------------------------------------
// K1: weights -> transposed bf16 + padded W2 strip
// ---------------------------------------------------------------------------
__global__ void prep_weights(const float* __restrict__ W0, const float* __restrict__ W1,
                             const float* __restrict__ W2,
                             unsigned short* __restrict__ w0t, unsigned short* __restrict__ w1t,
                             unsigned short* __restrict__ w2p) {
    int i = blockIdx.x * 256 + threadIdx.x;
    for (int idx = i; idx < 128 * 384; idx += gridDim.x * 256) {
        int j = idx / 384, k = idx - j * 384;
        w0t[idx] = f2b(W0[k * 128 + j]);
    }
    for (int idx = i; idx < 128 * 128; idx += gridDim.x * 256) {
        int j = idx >> 7, k = idx & 127;
        w1t[idx] = f2b(W1[k * 128 + j]);
    }
    for (int idx = i; idx < 16 * 128; idx += gridDim.x * 256) {
        int r = idx >> 7, k = idx & 127;
        w2p[idx] = (r < 2) ? f2b(W2[k * 2 + r]) : (unsigned short)0;
    }
}

// ---------------------------------------------------------------------------
// K2: fused. 1024 thr = 16 waves (4/SIMD mandatory), m=1 (16 pts/wave).
// W0 in LDS (784B pitch); per-wave 2.3KB half-bounce (no barriers).
// LDS = 100352 + 16*2304 = 137216 B. Regs ~120 unified <= 128 cap.
// ---------------------------------------------------------------------------
#define W0P 784
#define HBW 144   // half-bounce row pitch in bytes (72 shorts)

__global__ __launch_bounds__(1024) void fused_decoder(
    const unsigned short* __restrict__ ht,
    const float* __restrict__ xs, const float* __restrict__ ys,
    const float* __restrict__ Bm,
    const unsigned short* __restrict__ w0t, const float* __restrict__ b0,
    const unsigned short* __restrict__ w1t, const float* __restrict__ b1,
    const unsigned short* __restrict__ w2p, const float* __restrict__ b2,
    float* __restrict__ out)
{
    __shared__ char smem[128 * W0P + 16 * 16 * HBW];   // 137216 B
    char* w0s = smem;
    int tid = threadIdx.x, lane = tid & 63, w = tid >> 6;
    int lr = lane & 15, lg = lane >> 4;
    char* hb = smem + 128 * W0P + w * 16 * HBW;

    // ---- stage W0 into LDS, 784B pitch (6144 chunks / 1024 thr = 6)
    {
        const short8* src = (const short8*)w0t;
#pragma unroll 1
        for (int it = 0; it < 6; ++it) {
            int c = tid + it * 1024;
            int row = c / 48, cc = c - row * 48;
            *(short8*)(w0s + row * W0P + cc * 16) = src[c];
        }
    }
    __syncthreads();

    int bid = blockIdx.x;                 // 1024 = 8 xcd * 128
    int x = bid & 7, s = bid >> 3;
    int n = x * 16 + (s >> 3);            // image 0..127 (same xcd as transpose)
    int pt = s & 7;                       // 256-pt tile
    int gp0 = n * 2048 + pt * 256 + w * 16;
    int gp = gp0 + lr;

    // ---- per-lane coords
    float xc = xs[gp], yc = ys[gp];
    float px = xc * 63.f, py = yc * 63.f;
    float x0f = fminf(fmaxf(floorf(px), 0.f), 63.f);
    float y0f = fminf(fmaxf(floorf(py), 0.f), 63.f);
    float wx = px - x0f, wy = py - y0f;
    float ivx = 1.f - wx, ivy = 1.f - wy;
    int xi0 = (int)x0f, yi0 = (int)y0f;
    int xi1 = min(xi0 + 1, 63), yi1 = min(yi0 + 1, 63);
    int o00 = (yi0 * 64 + xi0) * 256, o01 = (yi0 * 64 + xi1) * 256;
    int o10 = (yi1 * 64 + xi0) * 256, o11 = (yi1 * 64 + xi1) * 256;
    const char* base = (const char*)ht + ((size_t)n << 20) + lg * 16;

    // ================= layer 0 =================
    f32x4 acc[8];
#pragma unroll
    for (int nj = 0; nj < 8; ++nj) {
        float bv = b0[nj * 16 + lr];
        acc[nj] = (f32x4){bv, bv, bv, bv};
    }

    short8 A00, A01, A10, A11;            // even slices
    short8 B00, B01, B10, B11;            // odd slices
    A00 = *(const short8*)(base + o00);
    A01 = *(const short8*)(base + o01);
    A10 = *(const short8*)(base + o10);
    A11 = *(const short8*)(base + o11);
    B00 = *(const short8*)(base + o00 + 64);
    B01 = *(const short8*)(base + o01 + 64);
    B10 = *(const short8*)(base + o10 + 64);
    B11 = *(const short8*)(base + o11 + 64);

#pragma unroll 1
    for (int s2 = 0; s2 < 2; ++s2) {
#pragma unroll
        for (int half = 0; half < 2; ++half) {
            int q = 2 * s2 + half;
            // ---- fourier slice q (VALU cover for in-flight corner loads)
            short8 asn, acs;
            {
                int f0 = q * 32 + lg * 8;
                f32x4 B0a = *(const f32x4*)&Bm[f0];
                f32x4 B0b = *(const f32x4*)&Bm[f0 + 4];
                f32x4 B1a = *(const f32x4*)&Bm[128 + f0];
                f32x4 B1b = *(const f32x4*)&Bm[128 + f0 + 4];
                float t_[8];
#pragma unroll
                for (int jj = 0; jj < 4; ++jj) {
                    t_[jj]     = xc * B0a[jj] + yc * B1a[jj];
                    t_[4 + jj] = xc * B0b[jj] + yc * B1b[jj];
                }
#pragma unroll
                for (int jj = 0; jj < 8; ++jj) {
                    float tf = t_[jj] - floorf(t_[jj]);   // revolutions for HW trig
                    float sv, cv;
                    asm("v_sin_f32 %0, %1" : "=v"(sv) : "v"(tf));
                    asm("v_cos_f32 %0, %1" : "=v"(cv) : "v"(tf));
                    asn[jj] = (short)f2b(sv);
                    acs[jj] = (short)f2b(cv);
                }
            }
#pragma unroll
            for (int nj = 0; nj < 8; ++nj) {
                short8 bs = *(const short8*)(w0s + (nj * 16 + lr) * W0P + (4 + q) * 64 + lg * 16);
                acc[nj] = MFMA_BF16(asn, bs, acc[nj], 0, 0, 0);
            }
#pragma unroll
            for (int nj = 0; nj < 8; ++nj) {
                short8 bc = *(const short8*)(w0s + (nj * 16 + lr) * W0P + (8 + q) * 64 + lg * 16);
                acc[nj] = MFMA_BF16(acs, bc, acc[nj], 0, 0, 0);
            }
            // ---- lerp slice q from its set, reload that set 2 slices ahead
            short8 a;
            {
                short8 c0 = half ? B00 : A00, c1 = half ? B01 : A01;
                short8 c2 = half ? B10 : A10, c3 = half ? B11 : A11;
#pragma unroll
                for (int jj = 0; jj < 8; ++jj) {
                    float top = b2f((unsigned short)c0[jj]) * ivx + b2f((unsigned short)c1[jj]) * wx;
                    float bot = b2f((unsigned short)c2[jj]) * ivx + b2f((unsigned short)c3[jj]) * wx;
                    a[jj] = (short)f2b(top * ivy + bot * wy);
                }
            }
            if (s2 == 0) {
                int so = (q + 2) * 64;
                if (half == 0) {
                    A00 = *(const short8*)(base + o00 + so);
                    A01 = *(const short8*)(base + o01 + so);
                    A10 = *(const short8*)(base + o10 + so);
                    A11 = *(const short8*)(base + o11 + so);
                } else {
                    B00 = *(const short8*)(base + o00 + so);
                    B01 = *(const short8*)(base + o01 + so);
                    B10 = *(const short8*)(base + o10 + so);
                    B11 = *(const short8*)(base + o11 + so);
                }
            }
#pragma unroll
            for (int nj = 0; nj < 8; ++nj) {
                short8 b = *(const short8*)(w0s + (nj * 16 + lr) * W0P + q * 64 + lg * 16);
                acc[nj] = MFMA_BF16(a, b, acc[nj], 0, 0, 0);
            }
        }
    }

    // ====== layer 1: half-bounce D->A (per-wave private, no barriers) ======
    short8 a1[4];
#pragma unroll
    for (int hf = 0; hf < 2; ++hf) {
#pragma unroll
        for (int nj = 0; nj < 4; ++nj)
#pragma unroll
            for (int r = 0; r < 4; ++r) {
                int row = lg * 4 + r;
                *(unsigned short*)(hb + row * HBW + (nj * 16 + lr) * 2) =
                    f2b(fmaxf(acc[hf * 4 + nj][r], 0.f));
            }
        asm volatile("s_waitcnt lgkmcnt(0)" ::: "memory");
        a1[hf * 2]     = *(const short8*)(hb + lr * HBW + lg * 16);
        a1[hf * 2 + 1] = *(const short8*)(hb + lr * HBW + 64 + lg * 16);
        asm volatile("s_waitcnt lgkmcnt(0)" ::: "memory");
    }

#pragma unroll
    for (int nj = 0; nj < 8; ++nj) {
        float bv = b1[nj * 16 + lr];
        acc[nj] = (f32x4){bv, bv, bv, bv};
    }
#pragma unroll
    for (int ks = 0; ks < 4; ++ks)
#pragma unroll
        for (int nj = 0; nj < 8; ++nj) {
            short8 b = *(const short8*)&w1t[(nj * 16 + lr) * 128 + ks * 32 + lg * 8];
            acc[nj] = MFMA_BF16(a1[ks], b, acc[nj], 0, 0, 0);
        }

    // ====== layer 2: same half-bounce for h1 ======
    float bb2 = (lr < 2) ? b2[lr] : 0.f;
    f32x4 acc2 = (f32x4){bb2, bb2, bb2, bb2};
#pragma unroll
    for (int hf = 0; hf < 2; ++hf) {
#pragma unroll
        for (int nj = 0; nj < 4; ++nj)
#pragma unroll
            for (int r = 0; r < 4; ++r) {
                int row = lg * 4 + r;
                *(unsigned short*)(hb + row * HBW + (nj * 16 + lr) * 2) =
                    f2b(fmaxf(acc[hf * 4 + nj][r], 0.f));
            }
        asm volatile("s_waitcnt lgkmcnt(0)" ::: "memory");
#pragma unroll
        for (int k2 = 0; k2 < 2; ++k2) {
            int ks = hf * 2 + k2;
            short8 a2 = *(const short8*)(hb + lr * HBW + k2 * 64 + lg * 16);
            short8 bz = *(const short8*)&w2p[lr * 128 + ks * 32 + lg * 8];
            acc2 = MFMA_BF16(a2, bz, acc2, 0, 0, 0);
        }
        asm volatile("s_waitcnt lgkmcnt(0)" ::: "memory");
    }
    if (lr < 2) {
#pragma unroll
        for (int r = 0; r < 4; ++r) {
            int gpo = gp0 + lg * 4 + r;
            float v = acc2[r];
            if (lr == 0) {
                out[gpo * 2] = v;
            } else {
                float sp = (v > 20.f) ? v : log1pf(expf(v));
                out[gpo * 2 + 1] = sp + 0.01f;
            }
        }
    }
}

// ---------------------------------------------------------------------------
extern "C" void kernel_launch(void* const* d_in, const int* in_sizes, int n_in,
                              void* d_out, int out_size, void* d_ws, size_t ws_size,
                              hipStream_t stream) {
    const float* h_grid = (const float*)d_in[0];
    const float* xs = (const float*)d_in[1];
    const float* ys = (const float*)d_in[2];
    const float* Bm = (const float*)d_in[3];
    const float* W0 = (const float*)d_in[4];
    const float* b0 = (const float*)d_in[5];
    const float* W1 = (const float*)d_in[6];
    const float* b1 = (const float*)d_in[7];
    const float* W2 = (const float*)d_in[8];
    const float* b2 = (const float*)d_in[9];
    float* out = (float*)d_out;

    unsigned short* ht  = (unsigned short*)d_ws;
    unsigned short* w0t = (unsigned short*)((char*)d_ws + 134217728ull);
    unsigned short* w1t = w0t + 128 * 384;
    unsigned short* w2p = w1t + 128 * 128;

    transpose_h<<<dim3(8192), dim3(256), 0, stream>>>(h_grid, ht);
    prep_weights<<<dim3(64), dim3(256), 0, stream>>>(W0, W1, W2, w0t, w1t, w2p);
    fused_decoder<<<dim3(1024), dim3(1024), 0, stream>>>(ht, xs, ys, Bm, w0t, b0, w1t, b1, w2p, b2, out);
}